// Round 9
// baseline (33.985 us; speedup 1.0000x reference)
//
#include <hip/hip_runtime.h>

constexpr int NB = 256;
constexpr int OH = 112, OW = 96;
constexpr int IH = 224, IW = 192;
constexpr int NELEM = 256 * 3 * OH * OW;   // 8,257,536
constexpr int NVEC = NELEM / 4;            // 2,064,384
constexpr int PWORDS = 65536 / 8;          // 8192 u32 words, 8 u4 bins each (32 KB)
constexpr int HBLK = 512;                  // hist blocks: 2 per CU
constexpr int PPC = HBLK / 32;             // 16 partials per reduce chunk

typedef float f32x4 __attribute__((ext_vector_type(4)));

// ws layout (u32 words), S = HBLK*PWORDS = 4,194,304 (16 MB):
//   [0, S)          per-block u4-packed joint partials
//   S+0..255        hist_y (u32, device-scope atomics)
//   S+256           done counter (device-scope atomics)
//   S+512..S+1023   rowent (256 x f64, device-scope atomic stores/loads)

__device__ __forceinline__ void load_group(const float* __restrict__ x0,
                                           const float* __restrict__ img,
                                           int v, f32x4& im, f32x4& xa, f32x4& xc) {
    const int e  = v << 2;               // flat element index (multiple of 4)
    const int j  = e % OW;               // output col (multiple of 4)
    const int r  = e / OW;
    const int ii = r % OH;
    const int bc = r / OH;
    im = *reinterpret_cast<const f32x4*>(img + e);
    const int xb = (bc * IH + 2 * ii) * IW + 2 * j;   // 32B aligned
    xa = *reinterpret_cast<const f32x4*>(x0 + xb);
    xc = *reinterpret_cast<const f32x4*>(x0 + xb + 4);
}

__device__ __forceinline__ void scatter_group(unsigned int* __restrict__ jl,
                                              const f32x4& im, const f32x4& xa, const f32x4& xc) {
    const int b0 = ((int)im[0] << 8) | (int)xa[0];
    const int b1 = ((int)im[1] << 8) | (int)xa[2];
    const int b2 = ((int)im[2] << 8) | (int)xc[0];
    const int b3 = ((int)im[3] << 8) | (int)xc[2];
    atomicAdd(&jl[b0 >> 3], 1u << ((b0 & 7) * 4));   // u4 counters
    atomicAdd(&jl[b1 >> 3], 1u << ((b1 & 7) * 4));
    atomicAdd(&jl[b2 >> 3], 1u << ((b2 & 7) * 4));
    atomicAdd(&jl[b3 >> 3], 1u << ((b3 & 7) * 4));
}

// 512 blocks x 1024 threads, 2 blocks/CU (32 KB LDS each, VGPR capped for 8 waves/SIMD).
__global__ __launch_bounds__(1024, 8) void hist_part_k(const float* __restrict__ x0,
                                                       const float* __restrict__ img,
                                                       unsigned int* __restrict__ partial,
                                                       unsigned int* __restrict__ tail) {
    __shared__ unsigned int jl[PWORDS];      // 32 KB: 65536 u4 counters
    for (int w = threadIdx.x; w < PWORDS; w += 1024) jl[w] = 0u;
    if (blockIdx.x == 0) {                   // consumed only after kernel boundary
        if (threadIdx.x < NB) tail[threadIdx.x] = 0u;   // hist_y
        if (threadIdx.x == 0) tail[NB] = 0u;            // done counter
    }
    __syncthreads();

    const int stride = HBLK * 1024;          // 524288; NVEC = 3.9375 * stride
    int v = blockIdx.x * 1024 + threadIdx.x;
    for (; v + stride < NVEC; v += 2 * stride) { // pairwise: hoist 6 loads ahead of 8 atomics
        f32x4 im1, xa1, xc1, im2, xa2, xc2;
        load_group(x0, img, v,          im1, xa1, xc1);
        load_group(x0, img, v + stride, im2, xa2, xc2);
        scatter_group(jl, im1, xa1, xc1);
        scatter_group(jl, im2, xa2, xc2);
    }
    if (v < NVEC) {
        f32x4 im1, xa1, xc1;
        load_group(x0, img, v, im1, xa1, xc1);
        scatter_group(jl, im1, xa1, xc1);
    }
    __syncthreads();
    unsigned int* __restrict__ mine = partial + (size_t)blockIdx.x * PWORDS;
    for (int w = threadIdx.x; w < PWORDS; w += 1024) mine[w] = jl[w];
}

// 256 blocks (one joint ROW each) x 1024 threads; the LAST block to finish also
// computes the final scalar (all cross-block traffic is device-scope atomics).
// Row x occupies words [x*32, x*32+32); word w packs y-bins 8w..8w+7.
// Thread t: w = t&31, chunk c = t>>5 sums partials [16c, 16c+16) by nibble-pair
// into u16 halves (max 16*15=240); LDS tree over 32 chunks (global max ~194).
__global__ __launch_bounds__(1024) void reduce_k(const unsigned int* __restrict__ partial,
                                                 unsigned int* __restrict__ hist_y,
                                                 unsigned int* __restrict__ ctr,
                                                 unsigned long long* __restrict__ rowent,
                                                 float* __restrict__ out) {
    __shared__ unsigned int smem[4096];      // 16 KB
    __shared__ double ds[4];
    __shared__ unsigned int rss[4];
    __shared__ unsigned int is_last;
    const int tid = threadIdx.x;
    const int row = blockIdx.x;
    const double inv = 1.0 / 96.0;           // faithful quirk: normalizer = img.shape[-1]
    const double eps = 1e-8;

    {
        const int w = tid & 31, c = tid >> 5;
        unsigned int a0 = 0u, a1 = 0u, a2 = 0u, a3 = 0u;
        const unsigned int* __restrict__ pb =
            partial + (size_t)(c * PPC) * PWORDS + row * 32 + w;
        #pragma unroll
        for (int b = 0; b < PPC; ++b) {
            const unsigned int vv = pb[(size_t)b * PWORDS];
            a0 += vv         & 0x000F000Fu;    // nibbles 0,4 in u16 halves
            a1 += (vv >> 4)  & 0x000F000Fu;    // nibbles 1,5
            a2 += (vv >> 8)  & 0x000F000Fu;    // nibbles 2,6
            a3 += (vv >> 12) & 0x000F000Fu;    // nibbles 3,7
        }
        smem[0 * 1024 + c * 32 + w] = a0;
        smem[1 * 1024 + c * 32 + w] = a1;
        smem[2 * 1024 + c * 32 + w] = a2;
        smem[3 * 1024 + c * 32 + w] = a3;
        __syncthreads();
        for (int off = 16; off >= 1; off >>= 1) {
            if (c < off) {
                #pragma unroll
                for (int k = 0; k < 4; ++k)
                    smem[k * 1024 + c * 32 + w] += smem[k * 1024 + (c + off) * 32 + w];
            }
            __syncthreads();
        }
    }
    double s2 = 0.0;
    unsigned int rs = 0u, cnt = 0u;
    if (tid < 256) {
        const int w = tid >> 3, n = tid & 7, k = n & 3, half = n >> 2;
        cnt = (smem[k * 1024 + w] >> (16 * half)) & 0xFFFFu;   // chunk c==0 slot
        const double p = cnt * inv;
        s2 = p * log(p + eps);               // joint contribution (enters with +)
        rs = cnt;
        for (int off = 32; off > 0; off >>= 1) {
            s2 += __shfl_down(s2, off, 64);
            rs += __shfl_down(rs, off, 64);
        }
        if ((tid & 63) == 0) { ds[tid >> 6] = s2; rss[tid >> 6] = rs; }
    }
    __syncthreads();
    if (tid == 0) {
        const double sj = ds[0] + ds[1] + ds[2] + ds[3];
        const double px = (double)(rss[0] + rss[1] + rss[2] + rss[3]) * inv;
        const double re = sj - px * log(px + eps);   // fold -px*log(px) of this row
        __hip_atomic_store(&rowent[row], __builtin_bit_cast(unsigned long long, re),
                           __ATOMIC_RELAXED, __HIP_MEMORY_SCOPE_AGENT);
    }
    if (tid < 256 && cnt) atomicAdd(&hist_y[tid], cnt);

    __syncthreads();
    if (tid == 0) {
        const unsigned int old = __hip_atomic_fetch_add(ctr, 1u, __ATOMIC_ACQ_REL,
                                                        __HIP_MEMORY_SCOPE_AGENT);
        is_last = (old == (unsigned)(NB - 1)) ? 1u : 0u;
    }
    __syncthreads();
    if (!is_last) return;

    // ---- final scalar (fixed-order sum -> bit-deterministic) ----
    double acc = 0.0;
    if (tid < 256) {
        const unsigned int hy = __hip_atomic_load(&hist_y[tid], __ATOMIC_RELAXED,
                                                  __HIP_MEMORY_SCOPE_AGENT);
        const unsigned long long rb = __hip_atomic_load(&rowent[tid], __ATOMIC_RELAXED,
                                                        __HIP_MEMORY_SCOPE_AGENT);
        const double py = (double)hy * inv;
        acc = __builtin_bit_cast(double, rb) - py * log(py + eps);
        for (int off = 32; off > 0; off >>= 1) acc += __shfl_down(acc, off, 64);
        if ((tid & 63) == 0) ds[tid >> 6] = acc;
    }
    __syncthreads();
    if (tid == 0) out[0] = (float)(ds[0] + ds[1] + ds[2] + ds[3]);
}

// ============================ legacy fallback (small ws) ============================
__global__ __launch_bounds__(256) void zero_ws_k(unsigned int* __restrict__ ws) {
    int i = blockIdx.x * 256 + threadIdx.x;
    if (i < NB + NB + NB * NB) ws[i] = 0u;
}

__global__ __launch_bounds__(256) void hist_k(const float* __restrict__ x0,
                                              const float* __restrict__ img,
                                              unsigned int* __restrict__ ws) {
    __shared__ unsigned int sx[NB];
    __shared__ unsigned int sy[NB];
    if (threadIdx.x < NB) { sx[threadIdx.x] = 0u; sy[threadIdx.x] = 0u; }
    __syncthreads();
    unsigned int* __restrict__ joint = ws + 2 * NB;
    const int stride = gridDim.x * blockDim.x;
    for (int v = blockIdx.x * blockDim.x + threadIdx.x; v < NVEC; v += stride) {
        const int e  = v << 2;
        const int j  = e % OW;
        const int r  = e / OW;
        const int ii = r % OH;
        const int bc = r / OH;
        const float4 im = *reinterpret_cast<const float4*>(img + e);
        const int xb = (bc * IH + 2 * ii) * IW + 2 * j;
        const float4 xa = *reinterpret_cast<const float4*>(x0 + xb);
        const float4 xc = *reinterpret_cast<const float4*>(x0 + xb + 4);
        int ix[4] = { (int)im.x, (int)im.y, (int)im.z, (int)im.w };
        int iy[4] = { (int)xa.x, (int)xa.z, (int)xc.x, (int)xc.z };
        #pragma unroll
        for (int k = 0; k < 4; ++k) {
            atomicAdd(&sx[ix[k]], 1u);
            atomicAdd(&sy[iy[k]], 1u);
            atomicAdd(&joint[(ix[k] << 8) | iy[k]], 1u);
        }
    }
    __syncthreads();
    if (threadIdx.x < NB) {
        unsigned a = sx[threadIdx.x]; if (a) atomicAdd(ws + threadIdx.x, a);
        unsigned b = sy[threadIdx.x]; if (b) atomicAdd(ws + NB + threadIdx.x, b);
    }
}

__global__ __launch_bounds__(256) void entropy_k(const unsigned int* __restrict__ ws,
                                                 float* __restrict__ out) {
    const int t = threadIdx.x;
    const double inv = 1.0 / 96.0;
    const double eps = 1e-8;
    double acc = 0.0;
    {
        double px = ws[t] * inv;
        double py = ws[NB + t] * inv;
        acc -= px * log(px + eps);
        acc -= py * log(py + eps);
    }
    const unsigned int* __restrict__ joint = ws + 2 * NB;
    for (int k = 0; k < NB; ++k) {
        double p = joint[(t << 8) + k] * inv;
        acc += p * log(p + eps);
    }
    for (int off = 32; off > 0; off >>= 1) acc += __shfl_down(acc, off, 64);
    __shared__ double part[4];
    if ((t & 63) == 0) part[t >> 6] = acc;
    __syncthreads();
    if (t == 0) out[0] = (float)(part[0] + part[1] + part[2] + part[3]);
}

extern "C" void kernel_launch(void* const* d_in, const int* in_sizes, int n_in,
                              void* d_out, int out_size, void* d_ws, size_t ws_size,
                              hipStream_t stream) {
    const float* x0  = (const float*)d_in[0];   // (256,3,224,192)
    const float* img = (const float*)d_in[1];   // (256,3,112,96)
    unsigned int* ws = (unsigned int*)d_ws;
    float* out = (float*)d_out;

    const size_t S = (size_t)HBLK * PWORDS;                  // 4,194,304 words (16 MB)
    const size_t need_bytes = (S + 1024) * 4;                // ~16.8 MB
    if (ws_size >= need_bytes) {
        unsigned int*       partial = ws;
        unsigned int*       hist_y  = ws + S;
        unsigned int*       ctr     = ws + S + NB;
        unsigned long long* rowent  = (unsigned long long*)(ws + S + 512);
        hist_part_k<<<HBLK, 1024, 0, stream>>>(x0, img, partial, hist_y);
        reduce_k<<<NB, 1024, 0, stream>>>(partial, hist_y, ctr, rowent, out);
    } else {
        const int nz = NB + NB + NB * NB;
        zero_ws_k<<<(nz + 255) / 256, 256, 0, stream>>>(ws);
        hist_k<<<2048, 256, 0, stream>>>(x0, img, ws);
        entropy_k<<<1, 256, 0, stream>>>(ws, out);
    }
}

// Round 10
// 31.406 us; speedup vs baseline: 1.0821x; 1.0821x over previous
//
#include <hip/hip_runtime.h>

constexpr int NB = 256;
constexpr int OH = 112, OW = 96;
constexpr int IH = 224, IW = 192;
constexpr int NELEM = 256 * 3 * OH * OW;   // 8,257,536
constexpr int NVEC = NELEM / 4;            // 2,064,384
constexpr int PWORDS = 65536 / 8;          // 8192 u32 words, 8 u4 bins each (32 KB)
constexpr int NBLK = 256;
// NVEC = 7.875 * (NBLK*1024): groups k=0..6 valid for all threads; k=7 iff bid<224.

typedef float f32x4 __attribute__((ext_vector_type(4)));

// ws layout (u32 words), S = NBLK*PWORDS = 2,097,152 (8 MB):
//   [0, S)          per-block u4-packed joint partials
//   S+0..255        hist_y (u32, device-scope atomics)
//   S+256           done counter (device-scope atomics)
//   S+512..S+1023   rowent (256 x f64, device-scope atomic stores/loads)

__device__ __forceinline__ void load_group(const float* __restrict__ x0,
                                           const float* __restrict__ img,
                                           int v, f32x4& im, f32x4& xa, f32x4& xc) {
    const int e  = v << 2;               // flat element index (multiple of 4)
    const int j  = e % OW;               // output col (multiple of 4)
    const int r  = e / OW;
    const int ii = r % OH;
    const int bc = r / OH;
    im = *reinterpret_cast<const f32x4*>(img + e);
    const int xb = (bc * IH + 2 * ii) * IW + 2 * j;   // 32B aligned
    xa = *reinterpret_cast<const f32x4*>(x0 + xb);
    xc = *reinterpret_cast<const f32x4*>(x0 + xb + 4);
}

__device__ __forceinline__ void scatter_group(unsigned int* __restrict__ jl,
                                              const f32x4& im, const f32x4& xa, const f32x4& xc) {
    const int b0 = ((int)im[0] << 8) | (int)xa[0];
    const int b1 = ((int)im[1] << 8) | (int)xa[2];
    const int b2 = ((int)im[2] << 8) | (int)xc[0];
    const int b3 = ((int)im[3] << 8) | (int)xc[2];
    atomicAdd(&jl[b0 >> 3], 1u << ((b0 & 7) * 4));   // u4 counters
    atomicAdd(&jl[b1 >> 3], 1u << ((b1 & 7) * 4));
    atomicAdd(&jl[b2 >> 3], 1u << ((b2 & 7) * 4));
    atomicAdd(&jl[b3 >> 3], 1u << ((b3 & 7) * 4));
}

__global__ __launch_bounds__(1024) void hist_part_k(const float* __restrict__ x0,
                                                    const float* __restrict__ img,
                                                    unsigned int* __restrict__ partial,
                                                    unsigned int* __restrict__ tail) {
    __shared__ unsigned int jl[PWORDS];      // 32 KB: 65536 u4 counters
    for (int w = threadIdx.x; w < PWORDS; w += 1024) jl[w] = 0u;
    if (blockIdx.x == 0) {                   // consumed only after kernel boundary
        if (threadIdx.x < NB) tail[threadIdx.x] = 0u;   // hist_y
        if (threadIdx.x == 0) tail[NB] = 0u;            // done counter
    }
    __syncthreads();

    const int stride = NBLK * 1024;          // 262144
    const int v0 = blockIdx.x * 1024 + threadIdx.x;   // < stride
    const bool has7 = (blockIdx.x < 224);    // block-uniform: 229376 = 224*1024

    // staged deep prefetch: 18 loads in flight before first scatter (plain
    // loads -- NT measurably hurt, round 7 vs 8), all statically indexed.
    f32x4 im[8], xa[8], xc[8];
    #pragma unroll
    for (int k = 0; k < 6; ++k) load_group(x0, img, v0 + k * stride, im[k], xa[k], xc[k]);
    scatter_group(jl, im[0], xa[0], xc[0]);
    scatter_group(jl, im[1], xa[1], xc[1]);
    load_group(x0, img, v0 + 6 * stride, im[6], xa[6], xc[6]);
    if (has7) load_group(x0, img, v0 + 7 * stride, im[7], xa[7], xc[7]);
    #pragma unroll
    for (int k = 2; k < 7; ++k) scatter_group(jl, im[k], xa[k], xc[k]);
    if (has7) scatter_group(jl, im[7], xa[7], xc[7]);

    __syncthreads();
    unsigned int* __restrict__ mine = partial + (size_t)blockIdx.x * PWORDS;
    for (int w = threadIdx.x; w < PWORDS; w += 1024) mine[w] = jl[w];
}

// 256 blocks (one joint ROW each) x 1024 threads; the LAST block to finish also
// computes the final scalar (all cross-block traffic is device-scope atomics).
// Row x occupies words [x*32, x*32+32); word w packs y-bins 8w..8w+7.
// Thread t: w = t&31, chunk c = t>>5 sums partials [8c, 8c+8) by nibble-pair
// into u16 halves (max 8*15=120); LDS tree over 32 chunks (global max ~194).
__global__ __launch_bounds__(1024) void reduce_k(const unsigned int* __restrict__ partial,
                                                 unsigned int* __restrict__ hist_y,
                                                 unsigned int* __restrict__ ctr,
                                                 unsigned long long* __restrict__ rowent,
                                                 float* __restrict__ out) {
    __shared__ unsigned int smem[4096];      // 16 KB
    __shared__ double ds[4];
    __shared__ unsigned int rss[4];
    __shared__ unsigned int is_last;
    const int tid = threadIdx.x;
    const int row = blockIdx.x;
    const double inv = 1.0 / 96.0;           // faithful quirk: normalizer = img.shape[-1]
    const double eps = 1e-8;

    {
        const int w = tid & 31, c = tid >> 5;
        unsigned int a0 = 0u, a1 = 0u, a2 = 0u, a3 = 0u;
        const unsigned int* __restrict__ pb =
            partial + (size_t)(c * 8) * PWORDS + row * 32 + w;
        #pragma unroll
        for (int b = 0; b < 8; ++b) {
            const unsigned int vv = pb[(size_t)b * PWORDS];
            a0 += vv         & 0x000F000Fu;    // nibbles 0,4 in u16 halves
            a1 += (vv >> 4)  & 0x000F000Fu;    // nibbles 1,5
            a2 += (vv >> 8)  & 0x000F000Fu;    // nibbles 2,6
            a3 += (vv >> 12) & 0x000F000Fu;    // nibbles 3,7
        }
        smem[0 * 1024 + c * 32 + w] = a0;
        smem[1 * 1024 + c * 32 + w] = a1;
        smem[2 * 1024 + c * 32 + w] = a2;
        smem[3 * 1024 + c * 32 + w] = a3;
        __syncthreads();
        for (int off = 16; off >= 1; off >>= 1) {
            if (c < off) {
                #pragma unroll
                for (int k = 0; k < 4; ++k)
                    smem[k * 1024 + c * 32 + w] += smem[k * 1024 + (c + off) * 32 + w];
            }
            __syncthreads();
        }
    }
    double s2 = 0.0;
    unsigned int rs = 0u, cnt = 0u;
    if (tid < 256) {
        const int w = tid >> 3, n = tid & 7, k = n & 3, half = n >> 2;
        cnt = (smem[k * 1024 + w] >> (16 * half)) & 0xFFFFu;   // chunk c==0 slot
        const double p = cnt * inv;
        s2 = p * log(p + eps);               // joint contribution (enters with +)
        rs = cnt;
        for (int off = 32; off > 0; off >>= 1) {
            s2 += __shfl_down(s2, off, 64);
            rs += __shfl_down(rs, off, 64);
        }
        if ((tid & 63) == 0) { ds[tid >> 6] = s2; rss[tid >> 6] = rs; }
    }
    __syncthreads();
    if (tid == 0) {
        const double sj = ds[0] + ds[1] + ds[2] + ds[3];
        const double px = (double)(rss[0] + rss[1] + rss[2] + rss[3]) * inv;
        const double re = sj - px * log(px + eps);   // fold -px*log(px) of this row
        __hip_atomic_store(&rowent[row], __builtin_bit_cast(unsigned long long, re),
                           __ATOMIC_RELAXED, __HIP_MEMORY_SCOPE_AGENT);
    }
    if (tid < 256 && cnt) atomicAdd(&hist_y[tid], cnt);

    __syncthreads();
    if (tid == 0) {
        const unsigned int old = __hip_atomic_fetch_add(ctr, 1u, __ATOMIC_ACQ_REL,
                                                        __HIP_MEMORY_SCOPE_AGENT);
        is_last = (old == (unsigned)(NB - 1)) ? 1u : 0u;
    }
    __syncthreads();
    if (!is_last) return;

    // ---- final scalar (fixed-order sum -> bit-deterministic) ----
    double acc = 0.0;
    if (tid < 256) {
        const unsigned int hy = __hip_atomic_load(&hist_y[tid], __ATOMIC_RELAXED,
                                                  __HIP_MEMORY_SCOPE_AGENT);
        const unsigned long long rb = __hip_atomic_load(&rowent[tid], __ATOMIC_RELAXED,
                                                        __HIP_MEMORY_SCOPE_AGENT);
        const double py = (double)hy * inv;
        acc = __builtin_bit_cast(double, rb) - py * log(py + eps);
        for (int off = 32; off > 0; off >>= 1) acc += __shfl_down(acc, off, 64);
        if ((tid & 63) == 0) ds[tid >> 6] = acc;
    }
    __syncthreads();
    if (tid == 0) out[0] = (float)(ds[0] + ds[1] + ds[2] + ds[3]);
}

// ============================ legacy fallback (small ws) ============================
__global__ __launch_bounds__(256) void zero_ws_k(unsigned int* __restrict__ ws) {
    int i = blockIdx.x * 256 + threadIdx.x;
    if (i < NB + NB + NB * NB) ws[i] = 0u;
}

__global__ __launch_bounds__(256) void hist_k(const float* __restrict__ x0,
                                              const float* __restrict__ img,
                                              unsigned int* __restrict__ ws) {
    __shared__ unsigned int sx[NB];
    __shared__ unsigned int sy[NB];
    if (threadIdx.x < NB) { sx[threadIdx.x] = 0u; sy[threadIdx.x] = 0u; }
    __syncthreads();
    unsigned int* __restrict__ joint = ws + 2 * NB;
    const int stride = gridDim.x * blockDim.x;
    for (int v = blockIdx.x * blockDim.x + threadIdx.x; v < NVEC; v += stride) {
        const int e  = v << 2;
        const int j  = e % OW;
        const int r  = e / OW;
        const int ii = r % OH;
        const int bc = r / OH;
        const float4 im = *reinterpret_cast<const float4*>(img + e);
        const int xb = (bc * IH + 2 * ii) * IW + 2 * j;
        const float4 xa = *reinterpret_cast<const float4*>(x0 + xb);
        const float4 xc = *reinterpret_cast<const float4*>(x0 + xb + 4);
        int ix[4] = { (int)im.x, (int)im.y, (int)im.z, (int)im.w };
        int iy[4] = { (int)xa.x, (int)xa.z, (int)xc.x, (int)xc.z };
        #pragma unroll
        for (int k = 0; k < 4; ++k) {
            atomicAdd(&sx[ix[k]], 1u);
            atomicAdd(&sy[iy[k]], 1u);
            atomicAdd(&joint[(ix[k] << 8) | iy[k]], 1u);
        }
    }
    __syncthreads();
    if (threadIdx.x < NB) {
        unsigned a = sx[threadIdx.x]; if (a) atomicAdd(ws + threadIdx.x, a);
        unsigned b = sy[threadIdx.x]; if (b) atomicAdd(ws + NB + threadIdx.x, b);
    }
}

__global__ __launch_bounds__(256) void entropy_k(const unsigned int* __restrict__ ws,
                                                 float* __restrict__ out) {
    const int t = threadIdx.x;
    const double inv = 1.0 / 96.0;
    const double eps = 1e-8;
    double acc = 0.0;
    {
        double px = ws[t] * inv;
        double py = ws[NB + t] * inv;
        acc -= px * log(px + eps);
        acc -= py * log(py + eps);
    }
    const unsigned int* __restrict__ joint = ws + 2 * NB;
    for (int k = 0; k < NB; ++k) {
        double p = joint[(t << 8) + k] * inv;
        acc += p * log(p + eps);
    }
    for (int off = 32; off > 0; off >>= 1) acc += __shfl_down(acc, off, 64);
    __shared__ double part[4];
    if ((t & 63) == 0) part[t >> 6] = acc;
    __syncthreads();
    if (t == 0) out[0] = (float)(part[0] + part[1] + part[2] + part[3]);
}

extern "C" void kernel_launch(void* const* d_in, const int* in_sizes, int n_in,
                              void* d_out, int out_size, void* d_ws, size_t ws_size,
                              hipStream_t stream) {
    const float* x0  = (const float*)d_in[0];   // (256,3,224,192)
    const float* img = (const float*)d_in[1];   // (256,3,112,96)
    unsigned int* ws = (unsigned int*)d_ws;
    float* out = (float*)d_out;

    const size_t S = (size_t)NBLK * PWORDS;                  // 2,097,152 words (8 MB)
    const size_t need_bytes = (S + 1024) * 4;                // ~8.4 MB
    if (ws_size >= need_bytes) {
        unsigned int*       partial = ws;
        unsigned int*       hist_y  = ws + S;
        unsigned int*       ctr     = ws + S + NB;
        unsigned long long* rowent  = (unsigned long long*)(ws + S + 512);
        hist_part_k<<<NBLK, 1024, 0, stream>>>(x0, img, partial, hist_y);
        reduce_k<<<NB, 1024, 0, stream>>>(partial, hist_y, ctr, rowent, out);
    } else {
        const int nz = NB + NB + NB * NB;
        zero_ws_k<<<(nz + 255) / 256, 256, 0, stream>>>(ws);
        hist_k<<<2048, 256, 0, stream>>>(x0, img, ws);
        entropy_k<<<1, 256, 0, stream>>>(ws, out);
    }
}